// Round 18
// baseline (262.025 us; speedup 1.0000x reference)
//
#include <hip/hip_runtime.h>
#include <hip/hip_bf16.h>
#include <math.h>

#define BB 8
#define MM 8192
#define DD 512
#define RR 64
#define HH 128

typedef __attribute__((ext_vector_type(8))) short bf16x8;
typedef __attribute__((ext_vector_type(4))) short bf16x4;
typedef __attribute__((ext_vector_type(4))) float f32x4;

#define H_LD  136   // bf16 elems per h row  (128 + 8 pad)
#define AP_LD 132   // f32 elems per apply-LDS row (128 + 4 pad)

__device__ __forceinline__ float gelu_tanh(float x) {
    float u = 0.7978845608028654f * (x + 0.044715f * x * x * x);
    float e = __expf(2.0f * u);
    float t = 1.0f - 2.0f / (e + 1.0f);   // tanh(u)
    return 0.5f * x * (1.0f + t);
}

__device__ __forceinline__ short f2bf(float f) {   // round-to-nearest-even bf16
    unsigned int u = __float_as_uint(f);
    unsigned int r = u + 0x7FFFu + ((u >> 16) & 1u);
    return (short)(r >> 16);
}

// ---------------- prep: transpose-convert weights to bf16 [N][K] ----------------
__global__ __launch_bounds__(256) void prep_weights_kernel(
    const float* __restrict__ We1, const float* __restrict__ We2,
    short* __restrict__ We1T, short* __restrict__ We2T)
{
    int idx = blockIdx.x * 256 + threadIdx.x;
    if (idx < 128 * 512) {           // We1T[n][k] = bf16(We1[k][n])
        int n = idx >> 9, k = idx & 511;
        We1T[idx] = f2bf(We1[k * HH + n]);
    } else {
        int j = idx - 128 * 512;
        if (j < 64 * 128) {          // We2T[n][k] = bf16(We2[k][n])
            int n = j >> 7, k = j & 127;
            We2T[j] = f2bf(We2[k * RR + n]);
        }
    }
}

// ---------------- Kernel A: add path (R12-validated standalone) ----------------
__global__ __launch_bounds__(256) void add_path_kernel(
    const float* __restrict__ ot, const float* __restrict__ scale,
    const float* __restrict__ bias, const float* __restrict__ Wa1,
    const float* __restrict__ ba1, const float* __restrict__ Wa2,
    const float* __restrict__ ba2, float* __restrict__ add_out)
{
    int tid = threadIdx.x;
    int b = blockIdx.x >> 6, r = blockIdx.x & 63;
    const float* x = ot + (size_t)(b * RR + r) * DD;
    __shared__ float xs[DD];
    __shared__ float hsm[HH];
    __shared__ float rs[4], rq[4];
    float v0 = x[tid], v1 = x[tid + 256];
    float s = v0 + v1, q = v0 * v0 + v1 * v1;
    #pragma unroll
    for (int off = 32; off > 0; off >>= 1) { s += __shfl_xor(s, off); q += __shfl_xor(q, off); }
    if ((tid & 63) == 0) { rs[tid >> 6] = s; rq[tid >> 6] = q; }
    __syncthreads();
    s = rs[0] + rs[1] + rs[2] + rs[3];
    q = rq[0] + rq[1] + rq[2] + rq[3];
    float mean = s * (1.0f / DD);
    float var = q * (1.0f / DD) - mean * mean;
    float inv = rsqrtf(var + 1e-6f);
    xs[tid]       = (v0 - mean) * inv * scale[tid]       + bias[tid];
    xs[tid + 256] = (v1 - mean) * inv * scale[tid + 256] + bias[tid + 256];
    __syncthreads();
    if (tid < HH) {
        float acc = ba1[tid];
        for (int k = 0; k < DD; k++) acc = fmaf(xs[k], Wa1[k * HH + tid], acc);
        hsm[tid] = gelu_tanh(acc);
    }
    __syncthreads();
    int d0 = tid, d1 = tid + 256;
    float a0 = ba2[d0], a1 = ba2[d1];
    #pragma unroll 4
    for (int k = 0; k < HH; k++) {
        float hk = hsm[k];
        a0 = fmaf(hk, Wa2[k * DD + d0], a0);
        a1 = fmaf(hk, Wa2[k * DD + d1], a1);
    }
    add_out[(size_t)(b * RR + r) * DD + d0] = a0;
    add_out[(size_t)(b * RR + r) * DD + d1] = a1;
}

// ---------------- ln: pure streaming LN -> bf16 xnbf (no MFMA, no barriers) --------
// 16 rows/block, 16 threads/row, 8 independent float4 loads each; shfl-reduce.
__global__ __launch_bounds__(256) void ln_kernel(
    const float* __restrict__ mem, const float* __restrict__ scale,
    const float* __restrict__ bias, short* __restrict__ xnbf)
{
    int tid = threadIdx.x;
    int row16 = tid >> 4, sub = tid & 15;
    size_t grow = (size_t)blockIdx.x * 16 + row16;   // global row 0 .. BB*MM-1
    const float4* srcv = (const float4*)(mem + grow * DD);
    float4 v[8];
    #pragma unroll
    for (int j = 0; j < 8; j++) v[j] = srcv[j * 16 + sub];
    float s = 0.f, q = 0.f;
    #pragma unroll
    for (int j = 0; j < 8; j++) {
        s += v[j].x + v[j].y + v[j].z + v[j].w;
        q += v[j].x*v[j].x + v[j].y*v[j].y + v[j].z*v[j].z + v[j].w*v[j].w;
    }
    #pragma unroll
    for (int off = 1; off <= 8; off <<= 1) { s += __shfl_xor(s, off); q += __shfl_xor(q, off); }
    float mean = s * (1.0f / 512.0f);
    float var = q * (1.0f / 512.0f) - mean * mean;
    float inv = rsqrtf(var + 1e-6f);
    const float4* scv = (const float4*)scale;
    const float4* biv = (const float4*)bias;
    short* dst = xnbf + grow * DD;
    #pragma unroll
    for (int j = 0; j < 8; j++) {
        float4 sc = scv[j * 16 + sub], bi = biv[j * 16 + sub];
        bf16x4 o;
        o[0] = f2bf((v[j].x - mean) * inv * sc.x + bi.x);
        o[1] = f2bf((v[j].y - mean) * inv * sc.y + bi.y);
        o[2] = f2bf((v[j].z - mean) * inv * sc.z + bi.z);
        o[3] = f2bf((v[j].w - mean) * inv * sc.w + bi.w);
        *(bf16x4*)&dst[(j * 16 + sub) * 4] = o;
    }
}

// ---------------- erase GEMM: wave-autonomous, zero barriers -----------------------
// Each wave owns 16 rows. A-fragments load DIRECTLY from xnbf (L3-hot): lane
// (lr,kg) reads xnbf[row=m0+lr][ks*32+kg .. +7] -- the native MFMA A layout.
// B in-loop from L2. Per-wave LDS h-transpose (same-wave lgkmcnt, no barrier).
__global__ __launch_bounds__(256) void erase_gemm_kernel(
    const short* __restrict__ xnbf, const short* __restrict__ We1T,
    const float* __restrict__ be1, const short* __restrict__ We2T,
    const float* __restrict__ be2, short* __restrict__ logits_bf,
    float* __restrict__ psum)
{
    __shared__ short hs_all[4][16 * H_LD];   // 17,408 B

    int tid = threadIdx.x;
    int w = tid >> 6, l = tid & 63;
    int lr = l & 15, g = l >> 4, kg = g * 8;
    int gw = blockIdx.x * 4 + w;             // 0..4095
    int b = gw >> 9;
    int chunk = gw & 511;                    // 16-row chunk
    int m0 = chunk * 16;
    short* hsm = hs_all[w];

    const short* arow = xnbf + ((size_t)(b * MM + m0 + lr)) * DD + kg;

    // ---- GEMM1: [16 x 512] x [512 x 128]; A direct from global ----
    f32x4 acc[8];
    #pragma unroll
    for (int nf = 0; nf < 8; nf++) acc[nf] = (f32x4){0.f, 0.f, 0.f, 0.f};
    #pragma unroll 4
    for (int ks = 0; ks < 16; ks++) {
        bf16x8 a = *(const bf16x8*)(arow + ks * 32);
        #pragma unroll
        for (int nf = 0; nf < 8; nf++) {
            bf16x8 bf = *(const bf16x8*)(We1T + (size_t)(nf * 16 + lr) * 512 + ks * 32 + kg);
            acc[nf] = __builtin_amdgcn_mfma_f32_16x16x32_bf16(a, bf, acc[nf], 0, 0, 0);
        }
    }

    // ---- +bias, gelu -> per-wave hsm (no barrier; same-wave lgkmcnt ordering) ----
    #pragma unroll
    for (int nf = 0; nf < 8; nf++) {
        int col = nf * 16 + lr;
        float bv = be1[col];
        #pragma unroll
        for (int rg = 0; rg < 4; rg++)
            hsm[(g * 4 + rg) * H_LD + col] = f2bf(gelu_tanh(acc[nf][rg] + bv));
    }

    // ---- GEMM2: [16 x 128] x [128 x 64] ----
    f32x4 c2[4];
    #pragma unroll
    for (int nf = 0; nf < 4; nf++) c2[nf] = (f32x4){0.f, 0.f, 0.f, 0.f};
    #pragma unroll
    for (int ks = 0; ks < 4; ks++) {
        bf16x8 a2 = *(const bf16x8*)&hsm[lr * H_LD + ks * 32 + kg];
        #pragma unroll
        for (int nf = 0; nf < 4; nf++) {
            bf16x8 bf = *(const bf16x8*)(We2T + (nf * 16 + lr) * 128 + ks * 32 + kg);
            c2[nf] = __builtin_amdgcn_mfma_f32_16x16x32_bf16(a2, bf, c2[nf], 0, 0, 0);
        }
    }

    // ---- +bias, store bf16 exp(logit), per-16-row column sum ----
    #pragma unroll
    for (int nf = 0; nf < 4; nf++) {
        int c = nf * 16 + lr;
        float bv = be2[c];
        float sm = 0.f;
        #pragma unroll
        for (int rg = 0; rg < 4; rg++) {
            float ev = __expf(c2[nf][rg] + bv);
            sm += ev;
            logits_bf[(size_t)(b * MM + m0 + g * 4 + rg) * 64 + c] = f2bf(ev);
        }
        sm += __shfl_xor(sm, 16);
        sm += __shfl_xor(sm, 32);
        if (g == 0)
            psum[((size_t)b * 512 + chunk) * 64 + c] = sm;
    }
}

// ---------------- finalize: rinv = 1/sum, then scale+transpose add -> addT ----------
// rinv is folded into addT ONLY (apply must NOT multiply by rinv again).
__global__ __launch_bounds__(256) void softmax_finalize_kernel(
    const float* __restrict__ psum, const float* __restrict__ add,
    float* __restrict__ rinv, short* __restrict__ addT)
{
    int b = blockIdx.x;
    int g = threadIdx.x >> 6, r = threadIdx.x & 63;
    __shared__ float sm_[4][64];
    __shared__ float rinvl[64];
    float sm = 0.0f;
    for (int ch = g; ch < 512; ch += 4)
        sm += psum[((size_t)b * 512 + ch) * 64 + r];
    sm_[g][r] = sm;
    __syncthreads();
    if (threadIdx.x < 64) {
        float S = sm_[0][threadIdx.x] + sm_[1][threadIdx.x]
                + sm_[2][threadIdx.x] + sm_[3][threadIdx.x];
        float rv = 1.0f / S;
        rinv[b * 64 + threadIdx.x] = rv;
        rinvl[threadIdx.x] = rv;
    }
    __syncthreads();
    const float* addb = add + (size_t)b * RR * DD;
    #pragma unroll 8
    for (int i = 0; i < 128; i++) {
        int idx = threadIdx.x + i * 256;          // 0..32767
        int d = idx >> 6, rr = idx & 63;
        addT[(size_t)b * 32768 + idx] = f2bf(addb[(size_t)rr * 512 + d] * rinvl[rr]);
    }
}

// ---------------- apply v5 (R17-validated): per-wave LDS bounce, full-line IO -------
__global__ __launch_bounds__(256, 4) void apply_mfma_kernel(
    const float* __restrict__ mem, const short* __restrict__ logits_bf,
    const short* __restrict__ addT, float* __restrict__ out)
{
    __shared__ float aplds[4][16 * AP_LD];   // 33,792 B
    int tid = threadIdx.x;
    int w = tid >> 6, l = tid & 63;
    int b = blockIdx.x >> 8;
    int mt = blockIdx.x & 255;
    int m0 = mt * 32;
    int lr = l & 15, g = l >> 4, kg = g * 8;
    int nbase = w * 128;
    const short* aT = addT + (size_t)b * 512 * 64;
    float* myl = aplds[w];

    int rrow = l >> 3, rc = l & 7;           // readback mapping: 8 rows x 8 lanes

    for (int ms = 0; ms < 2; ms++) {
        // ---- issue the 8 full-line float4 mem loads early (hidden under MFMA) ----
        float4 mvv[8];
        #pragma unroll
        for (int rb = 0; rb < 2; rb++) {
            int m = m0 + ms * 16 + rb * 8 + rrow;
            size_t gbase = (size_t)(b * MM + m) * DD + nbase;
            #pragma unroll
            for (int db = 0; db < 4; db++)
                mvv[rb * 4 + db] = *(const float4*)&mem[gbase + db * 32 + rc * 4];
        }

        // ---- A-fragments: direct 16B bf16 loads of exp-logits ----
        int mrow = m0 + ms * 16 + lr;
        const short* lp = logits_bf + (size_t)(b * MM + mrow) * 64 + kg;
        bf16x8 a0 = *(const bf16x8*)lp;
        bf16x8 a1 = *(const bf16x8*)(lp + 32);

        // ---- MFMA + stash acc in the wave's LDS tile ----
        #pragma unroll
        for (int nf = 0; nf < 8; nf++) {
            int d = nbase + nf * 16 + lr;
            bf16x8 b0 = *(const bf16x8*)&aT[d * 64 + kg];
            bf16x8 b1 = *(const bf16x8*)&aT[d * 64 + 32 + kg];
            f32x4 c = (f32x4){0.f, 0.f, 0.f, 0.f};
            c = __builtin_amdgcn_mfma_f32_16x16x32_bf16(a0, b0, c, 0, 0, 0);
            c = __builtin_amdgcn_mfma_f32_16x16x32_bf16(a1, b1, c, 0, 0, 0);
            #pragma unroll
            for (int rg = 0; rg < 4; rg++)
                myl[(g * 4 + rg) * AP_LD + nf * 16 + lr] = c[rg];
        }

        // ---- readback (same wave, lgkmcnt-ordered), blend, full-line store ----
        #pragma unroll
        for (int rb = 0; rb < 2; rb++) {
            int row = rb * 8 + rrow;
            int m = m0 + ms * 16 + row;
            size_t gbase = (size_t)(b * MM + m) * DD + nbase;
            #pragma unroll
            for (int db = 0; db < 4; db++) {
                float4 ea = *(const float4*)&myl[row * AP_LD + db * 32 + rc * 4];
                float4 mv = mvv[rb * 4 + db];
                float4 o;
                o.x = fmaf(ea.x, 1.0f - mv.x, mv.x);
                o.y = fmaf(ea.y, 1.0f - mv.y, mv.y);
                o.z = fmaf(ea.z, 1.0f - mv.z, mv.z);
                o.w = fmaf(ea.w, 1.0f - mv.w, mv.w);
                *(float4*)&out[gbase + db * 32 + rc * 4] = o;
            }
        }
    }
}

extern "C" void kernel_launch(void* const* d_in, const int* in_sizes, int n_in,
                              void* d_out, int out_size, void* d_ws, size_t ws_size,
                              hipStream_t stream) {
    const float* memory = (const float*)d_in[0];
    const float* ot     = (const float*)d_in[1];
    const float* ln_e_s = (const float*)d_in[2];
    const float* ln_e_b = (const float*)d_in[3];
    const float* We1    = (const float*)d_in[4];
    const float* be1    = (const float*)d_in[5];
    const float* We2    = (const float*)d_in[6];
    const float* be2    = (const float*)d_in[7];
    const float* ln_a_s = (const float*)d_in[8];
    const float* ln_a_b = (const float*)d_in[9];
    const float* Wa1    = (const float*)d_in[10];
    const float* ba1    = (const float*)d_in[11];
    const float* Wa2    = (const float*)d_in[12];
    const float* ba2    = (const float*)d_in[13];
    float* out = (float*)d_out;

    float* ws        = (float*)d_ws;
    float* add_ws    = ws;                        // 262,144 floats
    short* logits_bf = (short*)(ws + 262144);     // 4,194,304 bf16 (8 MB)
    float* psumw     = (float*)(logits_bf + 4194304);  // 262,144 floats
    float* rinvw     = psumw + 262144;            // 512
    short* We1T      = (short*)(rinvw + 512);     // 65,536 bf16
    short* We2T      = We1T + 128 * 512;          // 8,192 bf16
    short* addT      = We2T + 64 * 128;           // 262,144 bf16
    short* xnbf      = addT + 262144;             // 33,554,432 bf16 (67 MB)

    hipLaunchKernelGGL(prep_weights_kernel, dim3(288), dim3(256), 0, stream,
                       We1, We2, We1T, We2T);
    hipLaunchKernelGGL(add_path_kernel, dim3(BB * RR), dim3(256), 0, stream,
                       ot, ln_a_s, ln_a_b, Wa1, ba1, Wa2, ba2, add_ws);
    hipLaunchKernelGGL(ln_kernel, dim3(BB * MM / 16), dim3(256), 0, stream,
                       memory, ln_e_s, ln_e_b, xnbf);
    hipLaunchKernelGGL(erase_gemm_kernel, dim3(BB * 512 / 4), dim3(256), 0, stream,
                       xnbf, We1T, be1, We2T, be2, logits_bf, psumw);
    hipLaunchKernelGGL(softmax_finalize_kernel, dim3(BB), dim3(256), 0, stream,
                       psumw, add_ws, rinvw, addT);
    hipLaunchKernelGGL(apply_mfma_kernel, dim3(BB * 256), dim3(256), 0, stream,
                       memory, logits_bf, addT, out);
}

// Round 19
// 184.962 us; speedup vs baseline: 1.4166x; 1.4166x over previous
//
#include <hip/hip_runtime.h>
#include <hip/hip_bf16.h>
#include <math.h>

#define BB 8
#define MM 8192
#define DD 512
#define RR 64
#define HH 128

typedef __attribute__((ext_vector_type(8))) short bf16x8;
typedef __attribute__((ext_vector_type(4))) short bf16x4;
typedef __attribute__((ext_vector_type(4))) float f32x4;

#define XN_LD 520   // bf16 elems per xn row (512 + 8 pad)
#define H_LD  136   // bf16 elems per h row  (128 + 8 pad)
#define AP_LD 132   // f32 elems per apply-LDS row (128 + 4 pad)

__device__ __forceinline__ float gelu_tanh(float x) {
    float u = 0.7978845608028654f * (x + 0.044715f * x * x * x);
    float e = __expf(2.0f * u);
    float t = 1.0f - 2.0f / (e + 1.0f);   // tanh(u)
    return 0.5f * x * (1.0f + t);
}

__device__ __forceinline__ short f2bf(float f) {   // round-to-nearest-even bf16
    unsigned int u = __float_as_uint(f);
    unsigned int r = u + 0x7FFFu + ((u >> 16) & 1u);
    return (short)(r >> 16);
}

// ---------------- prep: transpose-convert weights to bf16 [N][K] ----------------
__global__ __launch_bounds__(256) void prep_weights_kernel(
    const float* __restrict__ We1, const float* __restrict__ We2,
    short* __restrict__ We1T, short* __restrict__ We2T)
{
    int idx = blockIdx.x * 256 + threadIdx.x;
    if (idx < 128 * 512) {           // We1T[n][k] = bf16(We1[k][n])
        int n = idx >> 9, k = idx & 511;
        We1T[idx] = f2bf(We1[k * HH + n]);
    } else {
        int j = idx - 128 * 512;
        if (j < 64 * 128) {          // We2T[n][k] = bf16(We2[k][n])
            int n = j >> 7, k = j & 127;
            We2T[j] = f2bf(We2[k * RR + n]);
        }
    }
}

// ---------------- Kernel A: add path (R12-validated standalone) ----------------
__global__ __launch_bounds__(256) void add_path_kernel(
    const float* __restrict__ ot, const float* __restrict__ scale,
    const float* __restrict__ bias, const float* __restrict__ Wa1,
    const float* __restrict__ ba1, const float* __restrict__ Wa2,
    const float* __restrict__ ba2, float* __restrict__ add_out)
{
    int tid = threadIdx.x;
    int b = blockIdx.x >> 6, r = blockIdx.x & 63;
    const float* x = ot + (size_t)(b * RR + r) * DD;
    __shared__ float xs[DD];
    __shared__ float hsm[HH];
    __shared__ float rs[4], rq[4];
    float v0 = x[tid], v1 = x[tid + 256];
    float s = v0 + v1, q = v0 * v0 + v1 * v1;
    #pragma unroll
    for (int off = 32; off > 0; off >>= 1) { s += __shfl_xor(s, off); q += __shfl_xor(q, off); }
    if ((tid & 63) == 0) { rs[tid >> 6] = s; rq[tid >> 6] = q; }
    __syncthreads();
    s = rs[0] + rs[1] + rs[2] + rs[3];
    q = rq[0] + rq[1] + rq[2] + rq[3];
    float mean = s * (1.0f / DD);
    float var = q * (1.0f / DD) - mean * mean;
    float inv = rsqrtf(var + 1e-6f);
    xs[tid]       = (v0 - mean) * inv * scale[tid]       + bias[tid];
    xs[tid + 256] = (v1 - mean) * inv * scale[tid + 256] + bias[tid + 256];
    __syncthreads();
    if (tid < HH) {
        float acc = ba1[tid];
        for (int k = 0; k < DD; k++) acc = fmaf(xs[k], Wa1[k * HH + tid], acc);
        hsm[tid] = gelu_tanh(acc);
    }
    __syncthreads();
    int d0 = tid, d1 = tid + 256;
    float a0 = ba2[d0], a1 = ba2[d1];
    #pragma unroll 4
    for (int k = 0; k < HH; k++) {
        float hk = hsm[k];
        a0 = fmaf(hk, Wa2[k * DD + d0], a0);
        a1 = fmaf(hk, Wa2[k * DD + d1], a1);
    }
    add_out[(size_t)(b * RR + r) * DD + d0] = a0;
    add_out[(size_t)(b * RR + r) * DD + d1] = a1;
}

// ---------------- erase v6b (R12-validated): 4-chunk blocks, B-frag reuse -----------
__global__ __launch_bounds__(512) void erase_mfma_kernel(
    const float* __restrict__ mem, const float* __restrict__ scale,
    const float* __restrict__ bias, const short* __restrict__ We1T,
    const float* __restrict__ be1, const short* __restrict__ We2T,
    const float* __restrict__ be2, short* __restrict__ logits_bf,
    float* __restrict__ psum)
{
    __shared__ short xn[32 * XN_LD];     // 33,280 B; hsm overlays after GEMM1
    short* hsm = xn;

    int tid = threadIdx.x;
    int b = blockIdx.x >> 6;
    int cbase = (blockIdx.x & 63) * 4;   // first 32-row chunk of this block

    int w = tid >> 6, l = tid & 63;
    int lr = l & 15, g = l >> 4, kg = g * 8;
    int row = tid >> 4, sub = tid & 15;
    int mhalf = w & 1, nf2 = w >> 1;

    // ---- B-fragment prefetch, ONCE per block (reused across 4 chunks) ----
    const short* bp0 = We1T + ((size_t)(w * 16 + lr) << 9) + kg;
    bf16x8 bfr[16];
    #pragma unroll
    for (int ks = 0; ks < 16; ks++) bfr[ks] = *(const bf16x8*)(bp0 + ks * 32);
    const short* bp2 = We2T + (nf2 * 16 + lr) * 128 + kg;
    bf16x8 bfr2[4];
    #pragma unroll
    for (int ks = 0; ks < 4; ks++) bfr2[ks] = *(const bf16x8*)(bp2 + ks * 32);

    const float4* scv = (const float4*)scale;
    const float4* biv = (const float4*)bias;

    // ---- load chunk 0 rows ----
    float4 v[8];
    {
        const float4* srcv = (const float4*)(mem + (size_t)(b * MM + cbase * 32 + row) * DD);
        #pragma unroll
        for (int j = 0; j < 8; j++) v[j] = srcv[j * 16 + sub];
    }

    for (int c = 0; c < 4; c++) {
        int m0 = (cbase + c) * 32;

        // ---- LN from v -> xn (16 threads/row) ----
        {
            float s = 0.f, q = 0.f;
            #pragma unroll
            for (int j = 0; j < 8; j++) {
                s += v[j].x + v[j].y + v[j].z + v[j].w;
                q += v[j].x*v[j].x + v[j].y*v[j].y + v[j].z*v[j].z + v[j].w*v[j].w;
            }
            #pragma unroll
            for (int off = 1; off <= 8; off <<= 1) { s += __shfl_xor(s, off); q += __shfl_xor(q, off); }
            float mean = s * (1.0f / 512.0f);
            float var = q * (1.0f / 512.0f) - mean * mean;
            float inv = rsqrtf(var + 1e-6f);
            #pragma unroll
            for (int j = 0; j < 8; j++) {
                float4 sc = scv[j * 16 + sub], bi = biv[j * 16 + sub];
                bf16x4 o;
                o[0] = f2bf((v[j].x - mean) * inv * sc.x + bi.x);
                o[1] = f2bf((v[j].y - mean) * inv * sc.y + bi.y);
                o[2] = f2bf((v[j].z - mean) * inv * sc.z + bi.z);
                o[3] = f2bf((v[j].w - mean) * inv * sc.w + bi.w);
                *(bf16x4*)&xn[row * XN_LD + (j * 16 + sub) * 4] = o;
            }
        }
        __syncthreads();

        // ---- issue NEXT chunk's loads (overlap with both GEMMs) ----
        if (c < 3) {
            const float4* srcv = (const float4*)(mem + (size_t)(b * MM + m0 + 32 + row) * DD);
            #pragma unroll
            for (int j = 0; j < 8; j++) v[j] = srcv[j * 16 + sub];
        }

        // ---- GEMM1: wave w owns cols w*16..+15, rows 0..31 ----
        f32x4 acc0 = {0.f,0.f,0.f,0.f}, acc1 = acc0;
        #pragma unroll
        for (int ks = 0; ks < 16; ks++) {
            int k0 = ks * 32;
            bf16x8 a0 = *(const bf16x8*)&xn[lr * XN_LD + k0 + kg];
            bf16x8 a1 = *(const bf16x8*)&xn[(16 + lr) * XN_LD + k0 + kg];
            acc0 = __builtin_amdgcn_mfma_f32_16x16x32_bf16(a0, bfr[ks], acc0, 0, 0, 0);
            acc1 = __builtin_amdgcn_mfma_f32_16x16x32_bf16(a1, bfr[ks], acc1, 0, 0, 0);
        }
        __syncthreads();   // WAR: all waves done reading xn before hsm overlay writes
        {
            int col = w * 16 + lr;
            float bv = be1[col];
            #pragma unroll
            for (int rg = 0; rg < 4; rg++) {
                hsm[(g * 4 + rg) * H_LD + col]      = f2bf(gelu_tanh(acc0[rg] + bv));
                hsm[(16 + g * 4 + rg) * H_LD + col] = f2bf(gelu_tanh(acc1[rg] + bv));
            }
        }
        __syncthreads();

        // ---- GEMM2: wave w -> m-half (w&1), col-frag (w>>1) ----
        f32x4 c0 = {0.f,0.f,0.f,0.f};
        #pragma unroll
        for (int ks = 0; ks < 4; ks++) {
            bf16x8 a2 = *(const bf16x8*)&hsm[(mhalf * 16 + lr) * H_LD + ks * 32 + kg];
            c0 = __builtin_amdgcn_mfma_f32_16x16x32_bf16(a2, bfr2[ks], c0, 0, 0, 0);
        }
        // ---- +bias, store bf16 exp(logit), per-16-row column sum ----
        {
            int cc = nf2 * 16 + lr;
            float bv = be2[cc];
            float sm = 0.f;
            #pragma unroll
            for (int rg = 0; rg < 4; rg++) {
                float ev = __expf(c0[rg] + bv);
                sm += ev;
                logits_bf[(size_t)(b * MM + m0 + mhalf * 16 + g * 4 + rg) * 64 + cc] = f2bf(ev);
            }
            sm += __shfl_xor(sm, 16);
            sm += __shfl_xor(sm, 32);
            if (l < 16) {
                int ch2 = (m0 >> 4) + mhalf;       // 16-row chunk id: 0..511
                psum[((size_t)b * 512 + ch2) * 64 + cc] = sm;
            }
        }
        __syncthreads();   // WAR: GEMM2/hsm reads done before next LN writes xn
    }
}

// ---------------- finalize: rinv = 1/sum, then scale+transpose add -> addT ----------
// rinv is folded into addT ONLY (apply must NOT multiply by rinv again).
__global__ __launch_bounds__(256) void softmax_finalize_kernel(
    const float* __restrict__ psum, const float* __restrict__ add,
    float* __restrict__ rinv, short* __restrict__ addT)
{
    int b = blockIdx.x;
    int g = threadIdx.x >> 6, r = threadIdx.x & 63;
    __shared__ float sm_[4][64];
    __shared__ float rinvl[64];
    float sm = 0.0f;
    for (int ch = g; ch < 512; ch += 4)
        sm += psum[((size_t)b * 512 + ch) * 64 + r];
    sm_[g][r] = sm;
    __syncthreads();
    if (threadIdx.x < 64) {
        float S = sm_[0][threadIdx.x] + sm_[1][threadIdx.x]
                + sm_[2][threadIdx.x] + sm_[3][threadIdx.x];
        float rv = 1.0f / S;
        rinv[b * 64 + threadIdx.x] = rv;
        rinvl[threadIdx.x] = rv;
    }
    __syncthreads();
    const float* addb = add + (size_t)b * RR * DD;
    #pragma unroll 8
    for (int i = 0; i < 128; i++) {
        int idx = threadIdx.x + i * 256;          // 0..32767
        int d = idx >> 6, rr = idx & 63;
        addT[(size_t)b * 32768 + idx] = f2bf(addb[(size_t)rr * 512 + d] * rinvl[rr]);
    }
}

// ---------------- apply v5 (R17-validated): per-wave LDS bounce, full-line IO -------
__global__ __launch_bounds__(256, 4) void apply_mfma_kernel(
    const float* __restrict__ mem, const short* __restrict__ logits_bf,
    const short* __restrict__ addT, float* __restrict__ out)
{
    __shared__ float aplds[4][16 * AP_LD];   // 33,792 B
    int tid = threadIdx.x;
    int w = tid >> 6, l = tid & 63;
    int b = blockIdx.x >> 8;
    int mt = blockIdx.x & 255;
    int m0 = mt * 32;
    int lr = l & 15, g = l >> 4, kg = g * 8;
    int nbase = w * 128;
    const short* aT = addT + (size_t)b * 512 * 64;
    float* myl = aplds[w];

    int rrow = l >> 3, rc = l & 7;           // readback mapping: 8 rows x 8 lanes

    for (int ms = 0; ms < 2; ms++) {
        // ---- issue the 8 full-line float4 mem loads early (hidden under MFMA) ----
        float4 mvv[8];
        #pragma unroll
        for (int rb = 0; rb < 2; rb++) {
            int m = m0 + ms * 16 + rb * 8 + rrow;
            size_t gbase = (size_t)(b * MM + m) * DD + nbase;
            #pragma unroll
            for (int db = 0; db < 4; db++)
                mvv[rb * 4 + db] = *(const float4*)&mem[gbase + db * 32 + rc * 4];
        }

        // ---- A-fragments: direct 16B bf16 loads of exp-logits ----
        int mrow = m0 + ms * 16 + lr;
        const short* lp = logits_bf + (size_t)(b * MM + mrow) * 64 + kg;
        bf16x8 a0 = *(const bf16x8*)lp;
        bf16x8 a1 = *(const bf16x8*)(lp + 32);

        // ---- MFMA + stash acc in the wave's LDS tile ----
        #pragma unroll
        for (int nf = 0; nf < 8; nf++) {
            int d = nbase + nf * 16 + lr;
            bf16x8 b0 = *(const bf16x8*)&aT[d * 64 + kg];
            bf16x8 b1 = *(const bf16x8*)&aT[d * 64 + 32 + kg];
            f32x4 c = (f32x4){0.f, 0.f, 0.f, 0.f};
            c = __builtin_amdgcn_mfma_f32_16x16x32_bf16(a0, b0, c, 0, 0, 0);
            c = __builtin_amdgcn_mfma_f32_16x16x32_bf16(a1, b1, c, 0, 0, 0);
            #pragma unroll
            for (int rg = 0; rg < 4; rg++)
                myl[(g * 4 + rg) * AP_LD + nf * 16 + lr] = c[rg];
        }

        // ---- readback (same wave, lgkmcnt-ordered), blend, full-line store ----
        #pragma unroll
        for (int rb = 0; rb < 2; rb++) {
            int row = rb * 8 + rrow;
            int m = m0 + ms * 16 + row;
            size_t gbase = (size_t)(b * MM + m) * DD + nbase;
            #pragma unroll
            for (int db = 0; db < 4; db++) {
                float4 ea = *(const float4*)&myl[row * AP_LD + db * 32 + rc * 4];
                float4 mv = mvv[rb * 4 + db];
                float4 o;
                o.x = fmaf(ea.x, 1.0f - mv.x, mv.x);
                o.y = fmaf(ea.y, 1.0f - mv.y, mv.y);
                o.z = fmaf(ea.z, 1.0f - mv.z, mv.z);
                o.w = fmaf(ea.w, 1.0f - mv.w, mv.w);
                *(float4*)&out[gbase + db * 32 + rc * 4] = o;
            }
        }
    }
}

extern "C" void kernel_launch(void* const* d_in, const int* in_sizes, int n_in,
                              void* d_out, int out_size, void* d_ws, size_t ws_size,
                              hipStream_t stream) {
    const float* memory = (const float*)d_in[0];
    const float* ot     = (const float*)d_in[1];
    const float* ln_e_s = (const float*)d_in[2];
    const float* ln_e_b = (const float*)d_in[3];
    const float* We1    = (const float*)d_in[4];
    const float* be1    = (const float*)d_in[5];
    const float* We2    = (const float*)d_in[6];
    const float* be2    = (const float*)d_in[7];
    const float* ln_a_s = (const float*)d_in[8];
    const float* ln_a_b = (const float*)d_in[9];
    const float* Wa1    = (const float*)d_in[10];
    const float* ba1    = (const float*)d_in[11];
    const float* Wa2    = (const float*)d_in[12];
    const float* ba2    = (const float*)d_in[13];
    float* out = (float*)d_out;

    float* ws        = (float*)d_ws;
    float* add_ws    = ws;                        // 262,144 floats
    short* logits_bf = (short*)(ws + 262144);     // 4,194,304 bf16 (8 MB)
    float* psumw     = (float*)(logits_bf + 4194304);  // 262,144 floats
    float* rinvw     = psumw + 262144;            // 512
    short* We1T      = (short*)(rinvw + 512);     // 65,536 bf16
    short* We2T      = We1T + 128 * 512;          // 8,192 bf16
    short* addT      = We2T + 64 * 128;           // 262,144 bf16

    hipLaunchKernelGGL(prep_weights_kernel, dim3(288), dim3(256), 0, stream,
                       We1, We2, We1T, We2T);
    hipLaunchKernelGGL(add_path_kernel, dim3(BB * RR), dim3(256), 0, stream,
                       ot, ln_a_s, ln_a_b, Wa1, ba1, Wa2, ba2, add_ws);
    hipLaunchKernelGGL(erase_mfma_kernel, dim3(BB * 64), dim3(512), 0, stream,
                       memory, ln_e_s, ln_e_b, We1T, be1, We2T, be2, logits_bf, psumw);
    hipLaunchKernelGGL(softmax_finalize_kernel, dim3(BB), dim3(256), 0, stream,
                       psumw, add_ws, rinvw, addT);
    hipLaunchKernelGGL(apply_mfma_kernel, dim3(BB * 256), dim3(256), 0, stream,
                       memory, logits_bf, addT, out);
}

// Round 20
// 173.421 us; speedup vs baseline: 1.5109x; 1.0666x over previous
//
#include <hip/hip_runtime.h>
#include <hip/hip_bf16.h>
#include <math.h>

#define BB 8
#define MM 8192
#define DD 512
#define RR 64
#define HH 128

typedef __attribute__((ext_vector_type(8))) short bf16x8;
typedef __attribute__((ext_vector_type(4))) short bf16x4;
typedef __attribute__((ext_vector_type(4))) float f32x4;

#define XN_LD 520   // bf16 elems per xn row (512 + 8 pad)
#define H_LD  136   // bf16 elems per h row  (128 + 8 pad)
#define AP_LD 132   // f32 elems per apply-LDS row (128 + 4 pad)

__device__ __forceinline__ float gelu_tanh(float x) {
    float u = 0.7978845608028654f * (x + 0.044715f * x * x * x);
    float e = __expf(2.0f * u);
    float t = 1.0f - 2.0f / (e + 1.0f);   // tanh(u)
    return 0.5f * x * (1.0f + t);
}

__device__ __forceinline__ short f2bf(float f) {   // round-to-nearest-even bf16
    unsigned int u = __float_as_uint(f);
    unsigned int r = u + 0x7FFFu + ((u >> 16) & 1u);
    return (short)(r >> 16);
}

// ---------------- fused prep+add: blocks 0..287 = weight transpose, 288..799 = add path
// Disjoint outputs; both read only kernel inputs. Saves one serial launch.
__global__ __launch_bounds__(256) void prep_add_kernel(
    const float* __restrict__ We1, const float* __restrict__ We2,
    short* __restrict__ We1T, short* __restrict__ We2T,
    const float* __restrict__ ot, const float* __restrict__ scale,
    const float* __restrict__ bias, const float* __restrict__ Wa1,
    const float* __restrict__ ba1, const float* __restrict__ Wa2,
    const float* __restrict__ ba2, float* __restrict__ add_out)
{
    int tid = threadIdx.x;
    if (blockIdx.x < 288) {
        // ---------------- prep: transpose-convert weights to bf16 [N][K] ----------
        int idx = blockIdx.x * 256 + tid;
        if (idx < 128 * 512) {           // We1T[n][k] = bf16(We1[k][n])
            int n = idx >> 9, k = idx & 511;
            We1T[idx] = f2bf(We1[k * HH + n]);
        } else {
            int j = idx - 128 * 512;
            if (j < 64 * 128) {          // We2T[n][k] = bf16(We2[k][n])
                int n = j >> 7, k = j & 127;
                We2T[j] = f2bf(We2[k * RR + n]);
            }
        }
        return;
    }
    // ---------------- add path (R12-validated body) --------------------------------
    int blk = blockIdx.x - 288;
    int b = blk >> 6, r = blk & 63;
    const float* x = ot + (size_t)(b * RR + r) * DD;
    __shared__ float xs[DD];
    __shared__ float hsm[HH];
    __shared__ float rs[4], rq[4];
    float v0 = x[tid], v1 = x[tid + 256];
    float s = v0 + v1, q = v0 * v0 + v1 * v1;
    #pragma unroll
    for (int off = 32; off > 0; off >>= 1) { s += __shfl_xor(s, off); q += __shfl_xor(q, off); }
    if ((tid & 63) == 0) { rs[tid >> 6] = s; rq[tid >> 6] = q; }
    __syncthreads();
    s = rs[0] + rs[1] + rs[2] + rs[3];
    q = rq[0] + rq[1] + rq[2] + rq[3];
    float mean = s * (1.0f / DD);
    float var = q * (1.0f / DD) - mean * mean;
    float inv = rsqrtf(var + 1e-6f);
    xs[tid]       = (v0 - mean) * inv * scale[tid]       + bias[tid];
    xs[tid + 256] = (v1 - mean) * inv * scale[tid + 256] + bias[tid + 256];
    __syncthreads();
    if (tid < HH) {
        float acc = ba1[tid];
        for (int k = 0; k < DD; k++) acc = fmaf(xs[k], Wa1[k * HH + tid], acc);
        hsm[tid] = gelu_tanh(acc);
    }
    __syncthreads();
    int d0 = tid, d1 = tid + 256;
    float a0 = ba2[d0], a1 = ba2[d1];
    #pragma unroll 4
    for (int k = 0; k < HH; k++) {
        float hk = hsm[k];
        a0 = fmaf(hk, Wa2[k * DD + d0], a0);
        a1 = fmaf(hk, Wa2[k * DD + d1], a1);
    }
    add_out[(size_t)(b * RR + r) * DD + d0] = a0;
    add_out[(size_t)(b * RR + r) * DD + d1] = a1;
}

// ---------------- erase v6b (R12-validated): 4-chunk blocks, B-frag reuse -----------
__global__ __launch_bounds__(512) void erase_mfma_kernel(
    const float* __restrict__ mem, const float* __restrict__ scale,
    const float* __restrict__ bias, const short* __restrict__ We1T,
    const float* __restrict__ be1, const short* __restrict__ We2T,
    const float* __restrict__ be2, short* __restrict__ logits_bf,
    float* __restrict__ psum)
{
    __shared__ short xn[32 * XN_LD];     // 33,280 B; hsm overlays after GEMM1
    short* hsm = xn;

    int tid = threadIdx.x;
    int b = blockIdx.x >> 6;
    int cbase = (blockIdx.x & 63) * 4;   // first 32-row chunk of this block

    int w = tid >> 6, l = tid & 63;
    int lr = l & 15, g = l >> 4, kg = g * 8;
    int row = tid >> 4, sub = tid & 15;
    int mhalf = w & 1, nf2 = w >> 1;

    // ---- B-fragment prefetch, ONCE per block (reused across 4 chunks) ----
    const short* bp0 = We1T + ((size_t)(w * 16 + lr) << 9) + kg;
    bf16x8 bfr[16];
    #pragma unroll
    for (int ks = 0; ks < 16; ks++) bfr[ks] = *(const bf16x8*)(bp0 + ks * 32);
    const short* bp2 = We2T + (nf2 * 16 + lr) * 128 + kg;
    bf16x8 bfr2[4];
    #pragma unroll
    for (int ks = 0; ks < 4; ks++) bfr2[ks] = *(const bf16x8*)(bp2 + ks * 32);

    const float4* scv = (const float4*)scale;
    const float4* biv = (const float4*)bias;

    // ---- load chunk 0 rows ----
    float4 v[8];
    {
        const float4* srcv = (const float4*)(mem + (size_t)(b * MM + cbase * 32 + row) * DD);
        #pragma unroll
        for (int j = 0; j < 8; j++) v[j] = srcv[j * 16 + sub];
    }

    for (int c = 0; c < 4; c++) {
        int m0 = (cbase + c) * 32;

        // ---- LN from v -> xn (16 threads/row) ----
        {
            float s = 0.f, q = 0.f;
            #pragma unroll
            for (int j = 0; j < 8; j++) {
                s += v[j].x + v[j].y + v[j].z + v[j].w;
                q += v[j].x*v[j].x + v[j].y*v[j].y + v[j].z*v[j].z + v[j].w*v[j].w;
            }
            #pragma unroll
            for (int off = 1; off <= 8; off <<= 1) { s += __shfl_xor(s, off); q += __shfl_xor(q, off); }
            float mean = s * (1.0f / 512.0f);
            float var = q * (1.0f / 512.0f) - mean * mean;
            float inv = rsqrtf(var + 1e-6f);
            #pragma unroll
            for (int j = 0; j < 8; j++) {
                float4 sc = scv[j * 16 + sub], bi = biv[j * 16 + sub];
                bf16x4 o;
                o[0] = f2bf((v[j].x - mean) * inv * sc.x + bi.x);
                o[1] = f2bf((v[j].y - mean) * inv * sc.y + bi.y);
                o[2] = f2bf((v[j].z - mean) * inv * sc.z + bi.z);
                o[3] = f2bf((v[j].w - mean) * inv * sc.w + bi.w);
                *(bf16x4*)&xn[row * XN_LD + (j * 16 + sub) * 4] = o;
            }
        }
        __syncthreads();

        // ---- issue NEXT chunk's loads (overlap with both GEMMs) ----
        if (c < 3) {
            const float4* srcv = (const float4*)(mem + (size_t)(b * MM + m0 + 32 + row) * DD);
            #pragma unroll
            for (int j = 0; j < 8; j++) v[j] = srcv[j * 16 + sub];
        }

        // ---- GEMM1: wave w owns cols w*16..+15, rows 0..31 ----
        f32x4 acc0 = {0.f,0.f,0.f,0.f}, acc1 = acc0;
        #pragma unroll
        for (int ks = 0; ks < 16; ks++) {
            int k0 = ks * 32;
            bf16x8 a0 = *(const bf16x8*)&xn[lr * XN_LD + k0 + kg];
            bf16x8 a1 = *(const bf16x8*)&xn[(16 + lr) * XN_LD + k0 + kg];
            acc0 = __builtin_amdgcn_mfma_f32_16x16x32_bf16(a0, bfr[ks], acc0, 0, 0, 0);
            acc1 = __builtin_amdgcn_mfma_f32_16x16x32_bf16(a1, bfr[ks], acc1, 0, 0, 0);
        }
        __syncthreads();   // WAR: all waves done reading xn before hsm overlay writes
        {
            int col = w * 16 + lr;
            float bv = be1[col];
            #pragma unroll
            for (int rg = 0; rg < 4; rg++) {
                hsm[(g * 4 + rg) * H_LD + col]      = f2bf(gelu_tanh(acc0[rg] + bv));
                hsm[(16 + g * 4 + rg) * H_LD + col] = f2bf(gelu_tanh(acc1[rg] + bv));
            }
        }
        __syncthreads();

        // ---- GEMM2: wave w -> m-half (w&1), col-frag (w>>1) ----
        f32x4 c0 = {0.f,0.f,0.f,0.f};
        #pragma unroll
        for (int ks = 0; ks < 4; ks++) {
            bf16x8 a2 = *(const bf16x8*)&hsm[(mhalf * 16 + lr) * H_LD + ks * 32 + kg];
            c0 = __builtin_amdgcn_mfma_f32_16x16x32_bf16(a2, bfr2[ks], c0, 0, 0, 0);
        }
        // ---- +bias, store bf16 exp(logit), per-16-row column sum ----
        {
            int cc = nf2 * 16 + lr;
            float bv = be2[cc];
            float sm = 0.f;
            #pragma unroll
            for (int rg = 0; rg < 4; rg++) {
                float ev = __expf(c0[rg] + bv);
                sm += ev;
                logits_bf[(size_t)(b * MM + m0 + mhalf * 16 + g * 4 + rg) * 64 + cc] = f2bf(ev);
            }
            sm += __shfl_xor(sm, 16);
            sm += __shfl_xor(sm, 32);
            if (l < 16) {
                int ch2 = (m0 >> 4) + mhalf;       // 16-row chunk id: 0..511
                psum[((size_t)b * 512 + ch2) * 64 + cc] = sm;
            }
        }
        __syncthreads();   // WAR: GEMM2/hsm reads done before next LN writes xn
    }
}

// ---------------- finalize: rinv = 1/sum, then scale+transpose add -> addT ----------
// rinv is folded into addT ONLY (apply must NOT multiply by rinv again).
__global__ __launch_bounds__(256) void softmax_finalize_kernel(
    const float* __restrict__ psum, const float* __restrict__ add,
    float* __restrict__ rinv, short* __restrict__ addT)
{
    int b = blockIdx.x;
    int g = threadIdx.x >> 6, r = threadIdx.x & 63;
    __shared__ float sm_[4][64];
    __shared__ float rinvl[64];
    float sm = 0.0f;
    for (int ch = g; ch < 512; ch += 4)
        sm += psum[((size_t)b * 512 + ch) * 64 + r];
    sm_[g][r] = sm;
    __syncthreads();
    if (threadIdx.x < 64) {
        float S = sm_[0][threadIdx.x] + sm_[1][threadIdx.x]
                + sm_[2][threadIdx.x] + sm_[3][threadIdx.x];
        float rv = 1.0f / S;
        rinv[b * 64 + threadIdx.x] = rv;
        rinvl[threadIdx.x] = rv;
    }
    __syncthreads();
    const float* addb = add + (size_t)b * RR * DD;
    #pragma unroll 8
    for (int i = 0; i < 128; i++) {
        int idx = threadIdx.x + i * 256;          // 0..32767
        int d = idx >> 6, rr = idx & 63;
        addT[(size_t)b * 32768 + idx] = f2bf(addb[(size_t)rr * 512 + d] * rinvl[rr]);
    }
}

// ---------------- apply v5 (R17-validated): per-wave LDS bounce, full-line IO -------
__global__ __launch_bounds__(256, 4) void apply_mfma_kernel(
    const float* __restrict__ mem, const short* __restrict__ logits_bf,
    const short* __restrict__ addT, float* __restrict__ out)
{
    __shared__ float aplds[4][16 * AP_LD];   // 33,792 B
    int tid = threadIdx.x;
    int w = tid >> 6, l = tid & 63;
    int b = blockIdx.x >> 8;
    int mt = blockIdx.x & 255;
    int m0 = mt * 32;
    int lr = l & 15, g = l >> 4, kg = g * 8;
    int nbase = w * 128;
    const short* aT = addT + (size_t)b * 512 * 64;
    float* myl = aplds[w];

    int rrow = l >> 3, rc = l & 7;           // readback mapping: 8 rows x 8 lanes

    for (int ms = 0; ms < 2; ms++) {
        // ---- issue the 8 full-line float4 mem loads early (hidden under MFMA) ----
        float4 mvv[8];
        #pragma unroll
        for (int rb = 0; rb < 2; rb++) {
            int m = m0 + ms * 16 + rb * 8 + rrow;
            size_t gbase = (size_t)(b * MM + m) * DD + nbase;
            #pragma unroll
            for (int db = 0; db < 4; db++)
                mvv[rb * 4 + db] = *(const float4*)&mem[gbase + db * 32 + rc * 4];
        }

        // ---- A-fragments: direct 16B bf16 loads of exp-logits ----
        int mrow = m0 + ms * 16 + lr;
        const short* lp = logits_bf + (size_t)(b * MM + mrow) * 64 + kg;
        bf16x8 a0 = *(const bf16x8*)lp;
        bf16x8 a1 = *(const bf16x8*)(lp + 32);

        // ---- MFMA + stash acc in the wave's LDS tile ----
        #pragma unroll
        for (int nf = 0; nf < 8; nf++) {
            int d = nbase + nf * 16 + lr;
            bf16x8 b0 = *(const bf16x8*)&aT[d * 64 + kg];
            bf16x8 b1 = *(const bf16x8*)&aT[d * 64 + 32 + kg];
            f32x4 c = (f32x4){0.f, 0.f, 0.f, 0.f};
            c = __builtin_amdgcn_mfma_f32_16x16x32_bf16(a0, b0, c, 0, 0, 0);
            c = __builtin_amdgcn_mfma_f32_16x16x32_bf16(a1, b1, c, 0, 0, 0);
            #pragma unroll
            for (int rg = 0; rg < 4; rg++)
                myl[(g * 4 + rg) * AP_LD + nf * 16 + lr] = c[rg];
        }

        // ---- readback (same wave, lgkmcnt-ordered), blend, full-line store ----
        #pragma unroll
        for (int rb = 0; rb < 2; rb++) {
            int row = rb * 8 + rrow;
            int m = m0 + ms * 16 + row;
            size_t gbase = (size_t)(b * MM + m) * DD + nbase;
            #pragma unroll
            for (int db = 0; db < 4; db++) {
                float4 ea = *(const float4*)&myl[row * AP_LD + db * 32 + rc * 4];
                float4 mv = mvv[rb * 4 + db];
                float4 o;
                o.x = fmaf(ea.x, 1.0f - mv.x, mv.x);
                o.y = fmaf(ea.y, 1.0f - mv.y, mv.y);
                o.z = fmaf(ea.z, 1.0f - mv.z, mv.z);
                o.w = fmaf(ea.w, 1.0f - mv.w, mv.w);
                *(float4*)&out[gbase + db * 32 + rc * 4] = o;
            }
        }
    }
}

extern "C" void kernel_launch(void* const* d_in, const int* in_sizes, int n_in,
                              void* d_out, int out_size, void* d_ws, size_t ws_size,
                              hipStream_t stream) {
    const float* memory = (const float*)d_in[0];
    const float* ot     = (const float*)d_in[1];
    const float* ln_e_s = (const float*)d_in[2];
    const float* ln_e_b = (const float*)d_in[3];
    const float* We1    = (const float*)d_in[4];
    const float* be1    = (const float*)d_in[5];
    const float* We2    = (const float*)d_in[6];
    const float* be2    = (const float*)d_in[7];
    const float* ln_a_s = (const float*)d_in[8];
    const float* ln_a_b = (const float*)d_in[9];
    const float* Wa1    = (const float*)d_in[10];
    const float* ba1    = (const float*)d_in[11];
    const float* Wa2    = (const float*)d_in[12];
    const float* ba2    = (const float*)d_in[13];
    float* out = (float*)d_out;

    float* ws        = (float*)d_ws;
    float* add_ws    = ws;                        // 262,144 floats
    short* logits_bf = (short*)(ws + 262144);     // 4,194,304 bf16 (8 MB)
    float* psumw     = (float*)(logits_bf + 4194304);  // 262,144 floats
    float* rinvw     = psumw + 262144;            // 512
    short* We1T      = (short*)(rinvw + 512);     // 65,536 bf16
    short* We2T      = We1T + 128 * 512;          // 8,192 bf16
    short* addT      = We2T + 64 * 128;           // 262,144 bf16

    hipLaunchKernelGGL(prep_add_kernel, dim3(288 + BB * RR), dim3(256), 0, stream,
                       We1, We2, We1T, We2T,
                       ot, ln_a_s, ln_a_b, Wa1, ba1, Wa2, ba2, add_ws);
    hipLaunchKernelGGL(erase_mfma_kernel, dim3(BB * 64), dim3(512), 0, stream,
                       memory, ln_e_s, ln_e_b, We1T, be1, We2T, be2, logits_bf, psumw);
    hipLaunchKernelGGL(softmax_finalize_kernel, dim3(BB), dim3(256), 0, stream,
                       psumw, add_ws, rinvw, addT);
    hipLaunchKernelGGL(apply_mfma_kernel, dim3(BB * 256), dim3(256), 0, stream,
                       memory, logits_bf, addT, out);
}